// Round 8
// baseline (274.145 us; speedup 1.0000x reference)
//
#include <hip/hip_runtime.h>

// relative_depth_crit — R11: quarter-pass tile-sweep, raw-barrier pipeline.
// R10 post-mortem: per-ITERATION cost ~2.5K cyc regardless of tile bytes; the
// culprit is __syncthreads() = s_waitcnt vmcnt(0)+s_barrier draining the
// just-issued tile-(t+2) prefetch EVERY iteration (full load latency paid 80x).
// R8's counted-vmcnt ran on the slow LDS-DMA path; the fast VGPR-staging path
// never got non-draining barriers. R11: main-loop barrier = lgkmcnt(0) (LDS
// visibility only) + raw s_barrier; prefetch loads stay in flight across it
// (T4). ds_write of the staged regs next iteration carries the counted vmcnt
// wait with a full iteration of slack. Also TE=8192/T=40 (half the
// iterations) => cells swept in FOUR quarter-passes (cap 13824 = +13sigma),
// LDS ~124 KB. Decisive test of the ~10 B/cyc/CU stream-cap theory.

constexpr int B = 64;
constexpr int H = 512;
constexpr int W = 640;
constexpr int P = 100000;
constexpr int HWSZ = H * W;            // 327680 floats = 1.31 MB per batch
constexpr int N4B = P / 4;             // 25000 vec4 per batch
constexpr int NCHUNK = 4;              // blocks per batch
constexpr int C4 = N4B / NCHUNK;       // 6250 vec4 per block
constexpr int THREADS = 512;           // 8 waves
constexpr int NWAVE = 8;
constexpr int SLOTS = 13;              // ceil(6250/512) vec4 per thread
constexpr int NG = SLOTS * 8;          // 104 endpoints per thread
constexpr int NE = C4 * 8;             // 50000 endpoints per block
constexpr int TE = 8192;               // tile elems (32 KB); bin = key>>13
constexpr int T = HWSZ / TE;           // 40 tiles
constexpr int QT = 10;                 // tiles per quarter-pass
constexpr int NQ = 4;
constexpr int CCAP = 13824;            // per-quarter cells cap (12500 +13sigma)
constexpr int NBLK = B * NCHUNK;       // 256 = one block per CU
constexpr int VTAIL = C4 - (SLOTS - 1) * THREADS;   // 106: slot-12 validity
constexpr float INV_N = 1.0f / (float)(B * P);
constexpr float MARGIN = 1.0f;

typedef int vint4 __attribute__((ext_vector_type(4)));
typedef float vfloat4 __attribute__((ext_vector_type(4)));

__device__ __forceinline__ float loss_from(float za, float zb, int od) {
    float zd = za - zb;
    float gt = (float)(od - 1);           // {-1, 0, 1}
    float mask = fabsf(gt);               // {0, 1}
    float t = fminf(gt * zd, MARGIN);
    float l_rank = __logf(1.0f + __expf(-t));
    float l_eq = fmaxf(zd * zd, MARGIN * MARGIN);
    return mask * l_rank + (1.0f - mask) * l_eq;
}

// placement of quarter q: scatter still-pending keys whose bin is in
// [q*QT, q*QT+QT) into cells; key reg morphs into cell position; tm marks.
#define PLACE_Q(qv)                                                        \
    _Pragma("unroll")                                                      \
    for (int k = 0; k < NG; ++k) {                                         \
        bool valid = (k < (SLOTS - 1) * 8) || v12;                         \
        if (valid && !((dn[k >> 5] >> (k & 31)) & 1u)) {                   \
            unsigned kk = key[k];                                          \
            unsigned bin = kk >> 13;                                       \
            if (bin - (unsigned)((qv) * QT) < (unsigned)QT) {              \
                unsigned pos = atomicAdd(&cur[wid][bin], 1u);              \
                cells[pos] = kk & (unsigned)(TE - 1);                      \
                key[k] = pos;                                              \
                tm[k >> 5] |= (1u << (k & 31));                            \
            }                                                              \
        }                                                                  \
    }

// readback of the quarter marked in tm: pull z bits into key regs.
#define READBACK_TM()                                                      \
    _Pragma("unroll")                                                      \
    for (int k = 0; k < NG; ++k)                                           \
        if ((tm[k >> 5] >> (k & 31)) & 1u)                                 \
            key[k] = cells[key[k]];                                        \
    _Pragma("unroll")                                                      \
    for (int w_ = 0; w_ < 4; ++w_) { dn[w_] |= tm[w_]; tm[w_] = 0u; }

__global__ __launch_bounds__(THREADS) void rdc_sweep(
        const float* __restrict__ depth,
        const vint4* __restrict__ xA, const vint4* __restrict__ yA,
        const vint4* __restrict__ xB, const vint4* __restrict__ yB,
        const vint4* __restrict__ ord,
        float* __restrict__ partials) {
    __shared__ unsigned cells[CCAP];      //  55296 B: rel, then z bits
    __shared__ float tiles[2][TE];        //  65536 B, double-buffered
    __shared__ unsigned hist[NWAVE][T];   //   1280 B
    __shared__ unsigned cur[NWAVE][T];    //   1280 B
    __shared__ unsigned startR[T];        //    160 B: per-quarter-rebased starts
    __shared__ unsigned qcount[NQ];       //     16 B: entries per quarter
    __shared__ float wsum[NWAVE];         // total ~123.6 KB -> 1 block/CU

    // XCD pinning: grid 256 = 8 XCDs x 32 slots; batch b on XCD b&7.
    const int j = blockIdx.x;
    const int x = j & 7;
    const int g = j >> 3;
    const int chunk = g & 3;
    const int b = ((g >> 2) << 3) + x;

    const int tid = threadIdx.x;
    const int lane = tid & 63;
    const int wid = tid >> 6;

    const float* dimg = depth + (size_t)b * HWSZ;

    // zero replica histograms: 8*40 = 320 words
    if (tid < NWAVE * T) ((unsigned*)hist)[tid] = 0u;

    // ---- index phase: 104 register-held keys + packed ordinals ----
    const int base4 = b * N4B + chunk * C4;
    const bool v12 = (tid < VTAIL);
    unsigned key[NG];
    unsigned pack[SLOTS];
    #pragma unroll
    for (int i = 0; i < SLOTS; ++i) {
        int c = i * THREADS + tid;
        if (c > C4 - 1) c = C4 - 1;       // clamp tail (i==12, tid>=106)
        int idx = base4 + c;
        vint4 xa = __builtin_nontemporal_load(&xA[idx]);
        vint4 ya = __builtin_nontemporal_load(&yA[idx]);
        vint4 xb = __builtin_nontemporal_load(&xB[idx]);
        vint4 yb = __builtin_nontemporal_load(&yB[idx]);
        vint4 od = __builtin_nontemporal_load(&ord[idx]);
        key[i*8+0] = ya.x * W + xa.x;  key[i*8+1] = yb.x * W + xb.x;
        key[i*8+2] = ya.y * W + xa.y;  key[i*8+3] = yb.y * W + xb.y;
        key[i*8+4] = ya.z * W + xa.z;  key[i*8+5] = yb.z * W + xb.z;
        key[i*8+6] = ya.w * W + xa.w;  key[i*8+7] = yb.w * W + xb.w;
        pack[i] = (od.x & 3) | ((od.y & 3) << 2) | ((od.z & 3) << 4)
                | ((od.w & 3) << 6);
    }

    // depth prologue: tile 0 -> pA regs, tile 1 -> p regs (4 dwordx4 each)
    vfloat4 pA0, pA1, pA2, pA3, p0, p1, p2, p3;
    {
        const vfloat4* s0 = (const vfloat4*)dimg;
        pA0 = s0[tid];           pA1 = s0[512 + tid];
        pA2 = s0[1024 + tid];    pA3 = s0[1536 + tid];
        const vfloat4* s1 = (const vfloat4*)(dimg + TE);
        p0 = s1[tid];            p1 = s1[512 + tid];
        p2 = s1[1024 + tid];     p3 = s1[1536 + tid];
    }
    __syncthreads();                      // hist zeroed visible

    // ---- histogram ----
    #pragma unroll
    for (int k = 0; k < NG; ++k) {
        bool valid = (k < (SLOTS - 1) * 8) || v12;
        if (valid) atomicAdd(&hist[wid][key[k] >> 13], 1u);
    }
    __syncthreads();

    // ---- prefix scan (wave 0): lane = bin; quarter-rebased starts ----
    if (wid == 0) {
        unsigned h[NWAVE];
        unsigned tot = 0;
        if (lane < T) {
            #pragma unroll
            for (int w = 0; w < NWAVE; ++w) h[w] = hist[w][lane];
            #pragma unroll
            for (int w = 0; w < NWAVE; ++w) { unsigned t_ = h[w]; h[w] = tot; tot += t_; }
        }
        unsigned inc = tot;
        #pragma unroll
        for (int d = 1; d < 64; d <<= 1) {
            unsigned n = __shfl_up(inc, d, 64);
            if (lane >= d) inc += n;
        }
        unsigned excl = inc - tot;
        int qb = (lane < T) ? (lane / QT) * QT : 0;
        unsigned qs = __shfl(excl, qb, 64);            // all lanes participate
        unsigned qeA = __shfl(inc,  (lane & 3) * QT + QT - 1, 64);
        unsigned qsA = __shfl(excl, (lane & 3) * QT, 64);
        if (lane < T) {
            unsigned sR = excl - qs;
            startR[lane] = sR;
            #pragma unroll
            for (int w = 0; w < NWAVE; ++w) cur[w][lane] = sR + h[w];
        }
        if (lane < NQ) qcount[lane] = qeA - qsA;
    }
    __syncthreads();

    // ---- placement(0); write tile 0; final full drain before the loop ----
    unsigned dn[4] = {0u, 0u, 0u, 0u};    // resolved-key mask
    unsigned tm[4] = {0u, 0u, 0u, 0u};    // placed-this-quarter mask
    PLACE_Q(0)
    {
        vfloat4* d4 = (vfloat4*)&tiles[0][0];
        d4[tid] = pA0;           d4[512 + tid] = pA1;
        d4[1024 + tid] = pA2;    d4[1536 + tid] = pA3;
    }
    __syncthreads();                      // seals tile0+placement; vmcnt -> 0

    // ---- main sweep: raw barriers, vmcnt never drained in-loop ----
    // invariant at top of iter t: buf[t&1] = tile t (sealed); p* = tile t+1.
    #pragma unroll 1
    for (int t = 0; t < T; ++t) {
        if ((t % QT) == 0 && t > 0) {
            const int q = t / QT;
            READBACK_TM()                 // pull quarter q-1 z into key regs
            __syncthreads();
            PLACE_Q(q)                    // scatter quarter q entries
            __syncthreads();
        }
        if (t + 1 < T) {                  // stage tile t+1 (waits its loads)
            vfloat4* d4 = (vfloat4*)&tiles[(t + 1) & 1][0];
            d4[tid] = p0;            d4[512 + tid] = p1;
            d4[1024 + tid] = p2;     d4[1536 + tid] = p3;
        }
        if (t + 2 < T) {                  // issue tile t+2 (stays in flight
            const vfloat4* s4 = (const vfloat4*)(dimg + (size_t)(t + 2) * TE);
            p0 = s4[tid];            p1 = s4[512 + tid];   // across barriers)
            p2 = s4[1024 + tid];     p3 = s4[1536 + tid];
        }
        const float* tb = &tiles[t & 1][0];
        unsigned s = startR[t];
        unsigned e = ((t % QT) == QT - 1) ? qcount[t / QT] : startR[t + 1];
        for (unsigned u = s + tid; u < e; u += THREADS) {
            unsigned rel = cells[u];
            cells[u] = __float_as_uint(tb[rel]);
        }
        // LDS-visibility fence + raw barrier (no vmcnt drain — T4)
        asm volatile("s_waitcnt lgkmcnt(0)" ::: "memory");
        __builtin_amdgcn_sched_barrier(0);
        __builtin_amdgcn_s_barrier();
        __builtin_amdgcn_sched_barrier(0);
    }
    __syncthreads();

    // ---- readback(3) + loss ----
    READBACK_TM()
    float acc = 0.0f;
    #pragma unroll
    for (int i = 0; i < SLOTS; ++i) {
        float li = 0.0f;
        #pragma unroll
        for (int q = 0; q < 4; ++q) {
            float za = __uint_as_float(key[i*8 + 2*q]);
            float zb = __uint_as_float(key[i*8 + 2*q + 1]);
            li += loss_from(za, zb, (int)((pack[i] >> (2 * q)) & 3u));
        }
        if (i == SLOTS - 1) li *= (v12 ? 1.0f : 0.0f);
        acc += li;
    }

    // ---- wave + block reduction ----
    #pragma unroll
    for (int off2 = 32; off2 > 0; off2 >>= 1)
        acc += __shfl_down(acc, off2, 64);
    if (lane == 0) wsum[wid] = acc;
    __syncthreads();
    if (wid == 0) {
        float v = (lane < NWAVE) ? wsum[lane] : 0.0f;
        #pragma unroll
        for (int off2 = 4; off2 > 0; off2 >>= 1)
            v += __shfl_down(v, off2, 64);
        if (lane == 0) partials[j] = v;
    }
}

__global__ __launch_bounds__(256) void rdc_finalize(
        const float* __restrict__ partials, float* __restrict__ out, int n) {
    float acc = 0.0f;
    for (int k = threadIdx.x; k < n; k += 256)
        acc += partials[k];
    #pragma unroll
    for (int off = 32; off > 0; off >>= 1)
        acc += __shfl_down(acc, off, 64);
    __shared__ float wsum[4];
    int lane = threadIdx.x & 63;
    int wid  = threadIdx.x >> 6;
    if (lane == 0) wsum[wid] = acc;
    __syncthreads();
    if (wid == 0 && lane == 0)
        out[0] = (wsum[0] + wsum[1] + wsum[2] + wsum[3]) * INV_N;
}

extern "C" void kernel_launch(void* const* d_in, const int* in_sizes, int n_in,
                              void* d_out, int out_size, void* d_ws, size_t ws_size,
                              hipStream_t stream) {
    const float* depth = (const float*)d_in[0];
    const vint4* xA = (const vint4*)d_in[1];
    const vint4* yA = (const vint4*)d_in[2];
    const vint4* xB = (const vint4*)d_in[3];
    const vint4* yB = (const vint4*)d_in[4];
    const vint4* ord = (const vint4*)d_in[5];
    float* out = (float*)d_out;

    float* partials = (float*)d_ws;      // NBLK*4 = 1 KB, ws is plenty
    rdc_sweep<<<NBLK, THREADS, 0, stream>>>(depth, xA, yA, xB, yB, ord, partials);
    rdc_finalize<<<1, 256, 0, stream>>>(partials, out, NBLK);
}

// Round 9
// 274.110 us; speedup vs baseline: 1.0001x; 1.0001x over previous
//
#include <hip/hip_runtime.h>

// relative_depth_crit — R12: R11 despilled (__launch_bounds__(512,2)).
// R11 post-mortem: WRITE_SIZE 16KB -> 33MB + FETCH +15MB = scratch spill.
// Register demand ~190 (key[104]+pack[13]+8x vfloat4 prefetch+masks) but the
// compiler allocated 128 (default heuristic targets 4 waves/EU for 512-thr
// blocks) and spilled the prefetch regs -> hot loop serialized through
// scratch. Fix: __launch_bounds__(THREADS, 2) = 2 waves/EU = exactly our
// 1 block/CU occupancy -> VGPR budget 256. Everything else identical to R11:
// quarter-pass cells (54KB), TE=8192/T=40, raw lgkm-only barriers (prefetch
// loads stay in flight across iterations; ds_write's implicit vmcnt wait has
// a full iteration of slack). Token-cap floor for 28.3K lines/CU ~ 49us.

constexpr int B = 64;
constexpr int H = 512;
constexpr int W = 640;
constexpr int P = 100000;
constexpr int HWSZ = H * W;            // 327680 floats = 1.31 MB per batch
constexpr int N4B = P / 4;             // 25000 vec4 per batch
constexpr int NCHUNK = 4;              // blocks per batch
constexpr int C4 = N4B / NCHUNK;       // 6250 vec4 per block
constexpr int THREADS = 512;           // 8 waves
constexpr int NWAVE = 8;
constexpr int SLOTS = 13;              // ceil(6250/512) vec4 per thread
constexpr int NG = SLOTS * 8;          // 104 endpoints per thread
constexpr int NE = C4 * 8;             // 50000 endpoints per block
constexpr int TE = 8192;               // tile elems (32 KB); bin = key>>13
constexpr int T = HWSZ / TE;           // 40 tiles
constexpr int QT = 10;                 // tiles per quarter-pass
constexpr int NQ = 4;
constexpr int CCAP = 13824;            // per-quarter cells cap (12500 +13sigma)
constexpr int NBLK = B * NCHUNK;       // 256 = one block per CU
constexpr int VTAIL = C4 - (SLOTS - 1) * THREADS;   // 106: slot-12 validity
constexpr float INV_N = 1.0f / (float)(B * P);
constexpr float MARGIN = 1.0f;

typedef int vint4 __attribute__((ext_vector_type(4)));
typedef float vfloat4 __attribute__((ext_vector_type(4)));

__device__ __forceinline__ float loss_from(float za, float zb, int od) {
    float zd = za - zb;
    float gt = (float)(od - 1);           // {-1, 0, 1}
    float mask = fabsf(gt);               // {0, 1}
    float t = fminf(gt * zd, MARGIN);
    float l_rank = __logf(1.0f + __expf(-t));
    float l_eq = fmaxf(zd * zd, MARGIN * MARGIN);
    return mask * l_rank + (1.0f - mask) * l_eq;
}

// placement of quarter q: scatter still-pending keys whose bin is in
// [q*QT, q*QT+QT) into cells; key reg morphs into cell position; tm marks.
#define PLACE_Q(qv)                                                        \
    _Pragma("unroll")                                                      \
    for (int k = 0; k < NG; ++k) {                                         \
        bool valid = (k < (SLOTS - 1) * 8) || v12;                         \
        if (valid && !((dn[k >> 5] >> (k & 31)) & 1u)) {                   \
            unsigned kk = key[k];                                          \
            unsigned bin = kk >> 13;                                       \
            if (bin - (unsigned)((qv) * QT) < (unsigned)QT) {              \
                unsigned pos = atomicAdd(&cur[wid][bin], 1u);              \
                cells[pos] = kk & (unsigned)(TE - 1);                      \
                key[k] = pos;                                              \
                tm[k >> 5] |= (1u << (k & 31));                            \
            }                                                              \
        }                                                                  \
    }

// readback of the quarter marked in tm: pull z bits into key regs.
#define READBACK_TM()                                                      \
    _Pragma("unroll")                                                      \
    for (int k = 0; k < NG; ++k)                                           \
        if ((tm[k >> 5] >> (k & 31)) & 1u)                                 \
            key[k] = cells[key[k]];                                        \
    _Pragma("unroll")                                                      \
    for (int w_ = 0; w_ < 4; ++w_) { dn[w_] |= tm[w_]; tm[w_] = 0u; }

__global__ __launch_bounds__(THREADS, 2) void rdc_sweep(
        const float* __restrict__ depth,
        const vint4* __restrict__ xA, const vint4* __restrict__ yA,
        const vint4* __restrict__ xB, const vint4* __restrict__ yB,
        const vint4* __restrict__ ord,
        float* __restrict__ partials) {
    __shared__ unsigned cells[CCAP];      //  55296 B: rel, then z bits
    __shared__ float tiles[2][TE];        //  65536 B, double-buffered
    __shared__ unsigned hist[NWAVE][T];   //   1280 B
    __shared__ unsigned cur[NWAVE][T];    //   1280 B
    __shared__ unsigned startR[T];        //    160 B: per-quarter-rebased starts
    __shared__ unsigned qcount[NQ];       //     16 B: entries per quarter
    __shared__ float wsum[NWAVE];         // total ~123.6 KB -> 1 block/CU

    // XCD pinning: grid 256 = 8 XCDs x 32 slots; batch b on XCD b&7.
    const int j = blockIdx.x;
    const int x = j & 7;
    const int g = j >> 3;
    const int chunk = g & 3;
    const int b = ((g >> 2) << 3) + x;

    const int tid = threadIdx.x;
    const int lane = tid & 63;
    const int wid = tid >> 6;

    const float* dimg = depth + (size_t)b * HWSZ;

    // zero replica histograms: 8*40 = 320 words
    if (tid < NWAVE * T) ((unsigned*)hist)[tid] = 0u;

    // ---- index phase: 104 register-held keys + packed ordinals ----
    const int base4 = b * N4B + chunk * C4;
    const bool v12 = (tid < VTAIL);
    unsigned key[NG];
    unsigned pack[SLOTS];
    #pragma unroll
    for (int i = 0; i < SLOTS; ++i) {
        int c = i * THREADS + tid;
        if (c > C4 - 1) c = C4 - 1;       // clamp tail (i==12, tid>=106)
        int idx = base4 + c;
        vint4 xa = __builtin_nontemporal_load(&xA[idx]);
        vint4 ya = __builtin_nontemporal_load(&yA[idx]);
        vint4 xb = __builtin_nontemporal_load(&xB[idx]);
        vint4 yb = __builtin_nontemporal_load(&yB[idx]);
        vint4 od = __builtin_nontemporal_load(&ord[idx]);
        key[i*8+0] = ya.x * W + xa.x;  key[i*8+1] = yb.x * W + xb.x;
        key[i*8+2] = ya.y * W + xa.y;  key[i*8+3] = yb.y * W + xb.y;
        key[i*8+4] = ya.z * W + xa.z;  key[i*8+5] = yb.z * W + xb.z;
        key[i*8+6] = ya.w * W + xa.w;  key[i*8+7] = yb.w * W + xb.w;
        pack[i] = (od.x & 3) | ((od.y & 3) << 2) | ((od.z & 3) << 4)
                | ((od.w & 3) << 6);
    }

    // depth prologue: tile 0 -> pA regs, tile 1 -> p regs (4 dwordx4 each)
    vfloat4 pA0, pA1, pA2, pA3, p0, p1, p2, p3;
    {
        const vfloat4* s0 = (const vfloat4*)dimg;
        pA0 = s0[tid];           pA1 = s0[512 + tid];
        pA2 = s0[1024 + tid];    pA3 = s0[1536 + tid];
        const vfloat4* s1 = (const vfloat4*)(dimg + TE);
        p0 = s1[tid];            p1 = s1[512 + tid];
        p2 = s1[1024 + tid];     p3 = s1[1536 + tid];
    }
    __syncthreads();                      // hist zeroed visible

    // ---- histogram ----
    #pragma unroll
    for (int k = 0; k < NG; ++k) {
        bool valid = (k < (SLOTS - 1) * 8) || v12;
        if (valid) atomicAdd(&hist[wid][key[k] >> 13], 1u);
    }
    __syncthreads();

    // ---- prefix scan (wave 0): lane = bin; quarter-rebased starts ----
    if (wid == 0) {
        unsigned h[NWAVE];
        unsigned tot = 0;
        if (lane < T) {
            #pragma unroll
            for (int w = 0; w < NWAVE; ++w) h[w] = hist[w][lane];
            #pragma unroll
            for (int w = 0; w < NWAVE; ++w) { unsigned t_ = h[w]; h[w] = tot; tot += t_; }
        }
        unsigned inc = tot;
        #pragma unroll
        for (int d = 1; d < 64; d <<= 1) {
            unsigned n = __shfl_up(inc, d, 64);
            if (lane >= d) inc += n;
        }
        unsigned excl = inc - tot;
        int qb = (lane < T) ? (lane / QT) * QT : 0;
        unsigned qs = __shfl(excl, qb, 64);            // all lanes participate
        unsigned qeA = __shfl(inc,  (lane & 3) * QT + QT - 1, 64);
        unsigned qsA = __shfl(excl, (lane & 3) * QT, 64);
        if (lane < T) {
            unsigned sR = excl - qs;
            startR[lane] = sR;
            #pragma unroll
            for (int w = 0; w < NWAVE; ++w) cur[w][lane] = sR + h[w];
        }
        if (lane < NQ) qcount[lane] = qeA - qsA;
    }
    __syncthreads();

    // ---- placement(0); write tile 0; final full drain before the loop ----
    unsigned dn[4] = {0u, 0u, 0u, 0u};    // resolved-key mask
    unsigned tm[4] = {0u, 0u, 0u, 0u};    // placed-this-quarter mask
    PLACE_Q(0)
    {
        vfloat4* d4 = (vfloat4*)&tiles[0][0];
        d4[tid] = pA0;           d4[512 + tid] = pA1;
        d4[1024 + tid] = pA2;    d4[1536 + tid] = pA3;
    }
    __syncthreads();                      // seals tile0+placement; vmcnt -> 0

    // ---- main sweep: raw barriers, vmcnt never drained in-loop ----
    // invariant at top of iter t: buf[t&1] = tile t (sealed); p* = tile t+1.
    #pragma unroll 1
    for (int t = 0; t < T; ++t) {
        if ((t % QT) == 0 && t > 0) {
            const int q = t / QT;
            READBACK_TM()                 // pull quarter q-1 z into key regs
            __syncthreads();
            PLACE_Q(q)                    // scatter quarter q entries
            __syncthreads();
        }
        if (t + 1 < T) {                  // stage tile t+1 (waits its loads)
            vfloat4* d4 = (vfloat4*)&tiles[(t + 1) & 1][0];
            d4[tid] = p0;            d4[512 + tid] = p1;
            d4[1024 + tid] = p2;     d4[1536 + tid] = p3;
        }
        if (t + 2 < T) {                  // issue tile t+2 (stays in flight
            const vfloat4* s4 = (const vfloat4*)(dimg + (size_t)(t + 2) * TE);
            p0 = s4[tid];            p1 = s4[512 + tid];   // across barriers)
            p2 = s4[1024 + tid];     p3 = s4[1536 + tid];
        }
        const float* tb = &tiles[t & 1][0];
        unsigned s = startR[t];
        unsigned e = ((t % QT) == QT - 1) ? qcount[t / QT] : startR[t + 1];
        for (unsigned u = s + tid; u < e; u += THREADS) {
            unsigned rel = cells[u];
            cells[u] = __float_as_uint(tb[rel]);
        }
        // LDS-visibility fence + raw barrier (no vmcnt drain — T4)
        asm volatile("s_waitcnt lgkmcnt(0)" ::: "memory");
        __builtin_amdgcn_sched_barrier(0);
        __builtin_amdgcn_s_barrier();
        __builtin_amdgcn_sched_barrier(0);
    }
    __syncthreads();

    // ---- readback(3) + loss ----
    READBACK_TM()
    float acc = 0.0f;
    #pragma unroll
    for (int i = 0; i < SLOTS; ++i) {
        float li = 0.0f;
        #pragma unroll
        for (int q = 0; q < 4; ++q) {
            float za = __uint_as_float(key[i*8 + 2*q]);
            float zb = __uint_as_float(key[i*8 + 2*q + 1]);
            li += loss_from(za, zb, (int)((pack[i] >> (2 * q)) & 3u));
        }
        if (i == SLOTS - 1) li *= (v12 ? 1.0f : 0.0f);
        acc += li;
    }

    // ---- wave + block reduction ----
    #pragma unroll
    for (int off2 = 32; off2 > 0; off2 >>= 1)
        acc += __shfl_down(acc, off2, 64);
    if (lane == 0) wsum[wid] = acc;
    __syncthreads();
    if (wid == 0) {
        float v = (lane < NWAVE) ? wsum[lane] : 0.0f;
        #pragma unroll
        for (int off2 = 4; off2 > 0; off2 >>= 1)
            v += __shfl_down(v, off2, 64);
        if (lane == 0) partials[j] = v;
    }
}

__global__ __launch_bounds__(256) void rdc_finalize(
        const float* __restrict__ partials, float* __restrict__ out, int n) {
    float acc = 0.0f;
    for (int k = threadIdx.x; k < n; k += 256)
        acc += partials[k];
    #pragma unroll
    for (int off = 32; off > 0; off >>= 1)
        acc += __shfl_down(acc, off, 64);
    __shared__ float wsum[4];
    int lane = threadIdx.x & 63;
    int wid  = threadIdx.x >> 6;
    if (lane == 0) wsum[wid] = acc;
    __syncthreads();
    if (wid == 0 && lane == 0)
        out[0] = (wsum[0] + wsum[1] + wsum[2] + wsum[3]) * INV_N;
}

extern "C" void kernel_launch(void* const* d_in, const int* in_sizes, int n_in,
                              void* d_out, int out_size, void* d_ws, size_t ws_size,
                              hipStream_t stream) {
    const float* depth = (const float*)d_in[0];
    const vint4* xA = (const vint4*)d_in[1];
    const vint4* yA = (const vint4*)d_in[2];
    const vint4* xB = (const vint4*)d_in[3];
    const vint4* yB = (const vint4*)d_in[4];
    const vint4* ord = (const vint4*)d_in[5];
    float* out = (float*)d_out;

    float* partials = (float*)d_ws;      // NBLK*4 = 1 KB, ws is plenty
    rdc_sweep<<<NBLK, THREADS, 0, stream>>>(depth, xA, yA, xB, yB, ord, partials);
    rdc_finalize<<<1, 256, 0, stream>>>(partials, out, NBLK);
}